// Round 4
// baseline (665.515 us; speedup 1.0000x reference)
//
#include <hip/hip_runtime.h>

#define BB 16
#define CC 32
#define HH 256
#define WW 256

#define TWV 30    // valid conv2 output cols per block (conv1 computed on 32)
#define TH 8      // rows per iteration (4 waves x 2 rows)
#define NT 4      // conv2 iterations per block (conv1 does NT+1)
#define CIP 36    // padded ci stride: 72 B -> 2-way LDS banks (free), 8B-aligned

typedef short bf16x8 __attribute__((ext_vector_type(8)));
typedef float f32x16 __attribute__((ext_vector_type(16)));

struct alignas(8)  U2 { unsigned x, y; };
struct alignas(16) U4 { U2 lo, hi; };

__device__ __forceinline__ unsigned short f2bf(float f) {
    unsigned u = __float_as_uint(f);
    u += 0x7fffu + ((u >> 16) & 1u);   // RNE
    return (unsigned short)(u >> 16);
}

// HW packed f32->bf16 (RNE).
__device__ __forceinline__ unsigned cvtpk(float lo, float hi) {
    unsigned r;
    asm("v_cvt_pk_bf16_f32 %0, %1, %2" : "=v"(r) : "v"(lo), "v"(hi));
    return r;
}

// Pre-swizzle weights into per-lane MFMA A-fragment order, bf16:
// wq[layer][st(18)][half(2)][n=co(32)][j(8)], value = w[co][ci][pos]
// with pos = st>>1 (kh*3+kw), ci = (st&1)*16 + half*8 + j.
__global__ void wprep(const float* __restrict__ w1, const float* __restrict__ w2,
                      unsigned short* __restrict__ wq) {
    int idx = blockIdx.x * 256 + threadIdx.x;   // 0..9215
    if (idx >= 18 * 2 * 32 * 8) return;
    int j    = idx & 7;
    int n    = (idx >> 3) & 31;
    int half = (idx >> 8) & 1;
    int st   = idx >> 9;
    int s = st & 1, pos = st >> 1;
    int ci = s * 16 + half * 8 + j;
    int src = (n * CC + ci) * 9 + pos;
    wq[idx]        = f2bf(w1[src]);
    wq[9216 + idx] = f2bf(w2[src]);
}

// Fully fused: conv1 (bias1*gate, relu) -> LDS ring -> conv2 (bias2*gate, relu) + resid.
// T14 async-stage: global loads for tile i+1 issued before conv1(i)'s MFMA body.
__global__ __launch_bounds__(256, 2)
void conv_fused(const float* __restrict__ x,
                const unsigned short* __restrict__ wq,   // layer1 table; layer2 at +9216 ushorts
                const float* __restrict__ b1v,
                const float* __restrict__ b2v,
                const float* __restrict__ gate,
                float* __restrict__ out)
{
    __shared__ unsigned short xs[TH + 2][34][CIP];      // 10*34*36*2 = 24480 B
    __shared__ unsigned short hs[2][TH][34][CIP];       // 2*8*34*36*2 = 39168 B (cols 32,33 pad)
    __shared__ float gs[CC], bs1[CC], bs2[CC];

    const int t     = threadIdx.x;
    const int b     = blockIdx.z;
    const int x0    = blockIdx.x * TWV;
    const int ybase = blockIdx.y * (TH * NT);

    if (t < CC) {
        float gv = gate[b * CC + t];
        gs[t]  = gv > 0.f ? gv : 0.f;
        bs1[t] = b1v[t];
        bs2[t] = b2v[t];
    }

    const int lane = t & 63;
    const int wv   = t >> 6;       // wave 0..3
    const int col  = lane & 31;    // MFMA n (pixel/col) and A m (co) lane index
    const int half = lane >> 5;
    const int r0 = wv * 2, r1 = r0 + 1;

    // Both layers' weight fragments (L2-hot 36KB table).
    // NOTE: U4 = 8 ushorts, so layer-2 base is wq + 9216 (ushorts).
    bf16x8 wf1[18], wf2[18];
    const U4* wq1 = (const U4*)wq;
    const U4* wq2 = (const U4*)(wq + 9216);
    #pragma unroll
    for (int st = 0; st < 18; ++st) {
        wf1[st] = __builtin_bit_cast(bf16x8, wq1[(st * 2 + half) * 32 + col]);
        wf2[st] = __builtin_bit_cast(bf16x8, wq2[(st * 2 + half) * 32 + col]);
    }

    // Pixel-per-thread staging decomposition (340 = 10x34 pixels; 84 threads own 2).
    const int yA = t / 34,        xA = t - yA * 34;
    const int pB = 256 + t;
    const int yB = pB / 34,       xB = pB - yB * 34;
    const bool hasB = t < 84;
    const float* xb = x + (size_t)b * CC * HH * WW;

    // In-flight staging registers (T14 split): 64 VGPR, LDS binds occupancy anyway.
    float va[32], vb[32];

    // Issue global loads for x rows [rowT, rowT+9] x cols [x0-2, x0+31].
    auto stage_load = [&](int rowT) {
        #pragma unroll
        for (int j = 0; j < 32; ++j) { va[j] = 0.f; vb[j] = 0.f; }
        const int gyA = rowT + yA, gxA = x0 - 2 + xA;
        if (gyA >= 0 && gyA < HH && gxA >= 0 && gxA < WW) {
            const float* pa = xb + (gyA * WW + gxA);
            #pragma unroll
            for (int j = 0; j < 32; ++j) va[j] = pa[j * (HH * WW)];
        }
        const int gyB = rowT + yB, gxB = x0 - 2 + xB;
        if (hasB && gyB >= 0 && gyB < HH && gxB >= 0 && gxB < WW) {
            const float* pb = xb + (gyB * WW + gxB);
            #pragma unroll
            for (int j = 0; j < 32; ++j) vb[j] = pb[j * (HH * WW)];
        }
    };
    // Convert + write the in-flight registers into xs (fixed LDS slots).
    auto stage_write = [&]() {
        #pragma unroll
        for (int k = 0; k < 8; ++k) {
            U2 w; w.x = cvtpk(va[4 * k + 0], va[4 * k + 1]);
                  w.y = cvtpk(va[4 * k + 2], va[4 * k + 3]);
            *(U2*)&xs[yA][xA][4 * k] = w;
        }
        if (hasB) {
            #pragma unroll
            for (int k = 0; k < 8; ++k) {
                U2 w; w.x = cvtpk(vb[4 * k + 0], vb[4 * k + 1]);
                      w.y = cvtpk(vb[4 * k + 2], vb[4 * k + 3]);
                *(U2*)&xs[yB][xB][4 * k] = w;
            }
        }
    };

    // conv1 iteration i: rows gR = ybase-1+8i+r (r=0..7), cols gC = x0-1+c (c=0..31).
    // Output -> hs[i&1], zero-masked outside the image (conv2 SAME padding).
    auto conv1_iter = [&](int i) {
        f32x16 acc0 = {0,0,0,0,0,0,0,0,0,0,0,0,0,0,0,0};
        f32x16 acc1 = {0,0,0,0,0,0,0,0,0,0,0,0,0,0,0,0};
        const unsigned short* xsb0 = &xs[r0][col][half * 8];
        const unsigned short* xsb1 = &xs[r1][col][half * 8];
        #pragma unroll
        for (int st = 0; st < 18; ++st) {
            const int pos = st >> 1, s = st & 1;
            const int kh = pos / 3, kw = pos - kh * 3;
            const int off = (kh * 34 + kw) * CIP + s * 16;
            U4 xa, xv;
            xa.lo = *(const U2*)(xsb0 + off);
            xa.hi = *(const U2*)(xsb0 + off + 4);
            xv.lo = *(const U2*)(xsb1 + off);
            xv.hi = *(const U2*)(xsb1 + off + 4);
            acc0 = __builtin_amdgcn_mfma_f32_32x32x16_bf16(wf1[st], __builtin_bit_cast(bf16x8, xa), acc0, 0, 0, 0);
            acc1 = __builtin_amdgcn_mfma_f32_32x32x16_bf16(wf1[st], __builtin_bit_cast(bf16x8, xv), acc1, 0, 0, 0);
        }
        const int rowbase = ybase - 1 + 8 * i;
        const int gR0 = rowbase + r0, gR1 = rowbase + r1;
        const int gC  = x0 - 1 + col;
        const bool okC = (unsigned)gC < (unsigned)WW;
        const bool ok0 = okC && ((unsigned)gR0 < (unsigned)HH);
        const bool ok1 = okC && ((unsigned)gR1 < (unsigned)HH);
        unsigned short* h0 = &hs[i & 1][r0][col][0];
        unsigned short* h1 = &hs[i & 1][r1][col][0];
        #pragma unroll
        for (int g = 0; g < 4; ++g) {
            int c0 = 8 * g + 4 * half;    // regs 4g..4g+3 -> consecutive co
            float a0 = fmaxf((acc0[4 * g + 0] + bs1[c0 + 0]) * gs[c0 + 0], 0.f);
            float a1 = fmaxf((acc0[4 * g + 1] + bs1[c0 + 1]) * gs[c0 + 1], 0.f);
            float a2 = fmaxf((acc0[4 * g + 2] + bs1[c0 + 2]) * gs[c0 + 2], 0.f);
            float a3 = fmaxf((acc0[4 * g + 3] + bs1[c0 + 3]) * gs[c0 + 3], 0.f);
            if (!ok0) { a0 = 0.f; a1 = 0.f; a2 = 0.f; a3 = 0.f; }
            U2 w0; w0.x = cvtpk(a0, a1); w0.y = cvtpk(a2, a3);
            *(U2*)(h0 + c0) = w0;
            float d0 = fmaxf((acc1[4 * g + 0] + bs1[c0 + 0]) * gs[c0 + 0], 0.f);
            float d1 = fmaxf((acc1[4 * g + 1] + bs1[c0 + 1]) * gs[c0 + 1], 0.f);
            float d2 = fmaxf((acc1[4 * g + 2] + bs1[c0 + 2]) * gs[c0 + 2], 0.f);
            float d3 = fmaxf((acc1[4 * g + 3] + bs1[c0 + 3]) * gs[c0 + 3], 0.f);
            if (!ok1) { d0 = 0.f; d1 = 0.f; d2 = 0.f; d3 = 0.f; }
            U2 w1; w1.x = cvtpk(d0, d1); w1.y = cvtpk(d2, d3);
            *(U2*)(h1 + c0) = w1;
        }
    };

    // conv2 iteration j: output rows gO = ybase+8j+r, cols gX = x0+n (n<30 valid).
    // Input row gO-1+kh lives in hs bank (j+(q>>3))&1, slot q&7, q = r+kh.
    auto conv2_iter = [&](int j) {
        const int gO0 = ybase + 8 * j + r0;
        const int gO1 = gO0 + 1;
        const int gX  = x0 + col;
        const bool okN = (col < TWV) && (gX < WW);
        const float* rb = x + (size_t)b * CC * HH * WW;
        // Resid prefetch: issue before the MFMA body, consume in epilogue.
        float rr0[16], rr1[16];
        if (okN) {
            #pragma unroll
            for (int reg = 0; reg < 16; ++reg) {
                int co = (reg & 3) + 8 * (reg >> 2) + 4 * half;
                rr0[reg] = rb[(co * HH + gO0) * WW + gX];
                rr1[reg] = rb[(co * HH + gO1) * WW + gX];
            }
        }
        f32x16 acc0 = {0,0,0,0,0,0,0,0,0,0,0,0,0,0,0,0};
        f32x16 acc1 = {0,0,0,0,0,0,0,0,0,0,0,0,0,0,0,0};
        const unsigned short* hb0 = &hs[j & 1][0][0][0];
        const unsigned short* hb1 = &hs[(j + 1) & 1][0][0][0];
        if (wv < 3) {
            // q = r+kh <= 7: everything in bank j&1, constant offsets.
            const unsigned short* p0 = hb0 + (r0 * 34 + col) * CIP + half * 8;
            const unsigned short* p1 = hb0 + (r1 * 34 + col) * CIP + half * 8;
            #pragma unroll
            for (int st = 0; st < 18; ++st) {
                const int pos = st >> 1, s = st & 1;
                const int kh = pos / 3, kw = pos - kh * 3;
                const int off = (kh * 34 + kw) * CIP + s * 16;
                U4 xa, xv;
                xa.lo = *(const U2*)(p0 + off);
                xa.hi = *(const U2*)(p0 + off + 4);
                xv.lo = *(const U2*)(p1 + off);
                xv.hi = *(const U2*)(p1 + off + 4);
                acc0 = __builtin_amdgcn_mfma_f32_32x32x16_bf16(wf2[st], __builtin_bit_cast(bf16x8, xa), acc0, 0, 0, 0);
                acc1 = __builtin_amdgcn_mfma_f32_32x32x16_bf16(wf2[st], __builtin_bit_cast(bf16x8, xv), acc1, 0, 0, 0);
            }
        } else {
            // wv==3: r0=6, r1=7 -> q0 = 6+kh in {6,7,8}, q1 = 7+kh in {7,8,9}; bank split compile-time.
            const unsigned short* c0p = hb0 + col * CIP + half * 8;
            const unsigned short* c1p = hb1 + col * CIP + half * 8;
            #pragma unroll
            for (int st = 0; st < 18; ++st) {
                const int pos = st >> 1, s = st & 1;
                const int kh = pos / 3, kw = pos - kh * 3;
                const int q0 = 6 + kh, q1 = 7 + kh;
                const unsigned short* p0 = (q0 >= 8 ? c1p : c0p) + ((q0 & 7) * 34 + kw) * CIP + s * 16;
                const unsigned short* p1 = (q1 >= 8 ? c1p : c0p) + ((q1 & 7) * 34 + kw) * CIP + s * 16;
                U4 xa, xv;
                xa.lo = *(const U2*)(p0);
                xa.hi = *(const U2*)(p0 + 4);
                xv.lo = *(const U2*)(p1);
                xv.hi = *(const U2*)(p1 + 4);
                acc0 = __builtin_amdgcn_mfma_f32_32x32x16_bf16(wf2[st], __builtin_bit_cast(bf16x8, xa), acc0, 0, 0, 0);
                acc1 = __builtin_amdgcn_mfma_f32_32x32x16_bf16(wf2[st], __builtin_bit_cast(bf16x8, xv), acc1, 0, 0, 0);
            }
        }
        float* ob = out + (size_t)b * CC * HH * WW;
        if (okN) {
            #pragma unroll
            for (int reg = 0; reg < 16; ++reg) {
                int co = (reg & 3) + 8 * (reg >> 2) + 4 * half;
                int i0 = (co * HH + gO0) * WW + gX;
                int i1 = (co * HH + gO1) * WW + gX;
                float v0 = (acc0[reg] + bs2[co]) * gs[co];
                float v1 = (acc1[reg] + bs2[co]) * gs[co];
                ob[i0] = fmaxf(v0, 0.f) + rr0[reg];
                ob[i1] = fmaxf(v1, 0.f) + rr1[reg];
            }
        }
    };

    // ---- schedule: conv1 one iteration ahead of conv2; stage loads one ahead of writes ----
    stage_load(ybase - 2);
    stage_write();
    __syncthreads();                     // xs(0) ready (also fences gs/bs)
    stage_load(ybase - 2 + 8);           // loads for tile 1 fly under conv1(0)
    conv1_iter(0);
    #pragma unroll 1
    for (int i = 1; i <= NT; ++i) {
        __syncthreads();                 // B1: conv1(i-1) xs reads done; conv2(i-2) hs reads done
        stage_write();                   // xs <- tile i (loads long since returned)
        __syncthreads();                 // B2: xs(i) ready
        if (i < NT) stage_load(ybase - 2 + 8 * (i + 1));  // fly under conv1(i)+conv2(i-1)
        conv1_iter(i);                   // -> hs[i&1]
        __syncthreads();                 // B3: hs[i&1] visible
        conv2_iter(i - 1);               // reads hs[(i-1)&1] + hs[i&1] rows 0..1
    }
}

extern "C" void kernel_launch(void* const* d_in, const int* in_sizes, int n_in,
                              void* d_out, int out_size, void* d_ws, size_t ws_size,
                              hipStream_t stream) {
    const float* x  = (const float*)d_in[0];
    const float* gv = (const float*)d_in[1];
    const float* w1 = (const float*)d_in[2];
    const float* b1 = (const float*)d_in[3];
    const float* w2 = (const float*)d_in[4];
    const float* b2 = (const float*)d_in[5];
    float* out = (float*)d_out;

    unsigned short* wq = (unsigned short*)d_ws;   // 2 x 9216 bf16 frag tables

    wprep<<<36, 256, 0, stream>>>(w1, w2, wq);

    dim3 grid((WW + TWV - 1) / TWV, HH / (TH * NT), BB);  // (9, 8, 16) = 1152 blocks
    conv_fused<<<grid, 256, 0, stream>>>(x, wq, b1, b2, gv, out);
}

// Round 5
// 465.019 us; speedup vs baseline: 1.4312x; 1.4312x over previous
//
#include <hip/hip_runtime.h>

#define BB 16
#define CC 32
#define HH 256
#define WW 256

#define TWV 30    // valid conv2 output cols per block (conv1 computed on 32)
#define TH 8      // rows per iteration (4 waves x 2 rows)
#define NT 4      // conv2 iterations per block (conv1 does NT+1)
#define CIP 36    // padded ci stride: 72 B -> 2-way LDS banks (free), 8B-aligned

typedef short bf16x8 __attribute__((ext_vector_type(8)));
typedef float f32x16 __attribute__((ext_vector_type(16)));

struct alignas(8)  U2 { unsigned x, y; };
struct alignas(16) U4 { U2 lo, hi; };

__device__ __forceinline__ unsigned short f2bf(float f) {
    unsigned u = __float_as_uint(f);
    u += 0x7fffu + ((u >> 16) & 1u);   // RNE
    return (unsigned short)(u >> 16);
}

// HW packed f32->bf16 (RNE).
__device__ __forceinline__ unsigned cvtpk(float lo, float hi) {
    unsigned r;
    asm("v_cvt_pk_bf16_f32 %0, %1, %2" : "=v"(r) : "v"(lo), "v"(hi));
    return r;
}

// Pre-swizzle weights into per-lane MFMA A-fragment order, bf16:
// wq[layer][st(18)][half(2)][n=co(32)][j(8)], value = w[co][ci][pos]
// with pos = st>>1 (kh*3+kw), ci = (st&1)*16 + half*8 + j.
__global__ void wprep(const float* __restrict__ w1, const float* __restrict__ w2,
                      unsigned short* __restrict__ wq) {
    int idx = blockIdx.x * 256 + threadIdx.x;   // 0..9215
    if (idx >= 18 * 2 * 32 * 8) return;
    int j    = idx & 7;
    int n    = (idx >> 3) & 31;
    int half = (idx >> 8) & 1;
    int st   = idx >> 9;
    int s = st & 1, pos = st >> 1;
    int ci = s * 16 + half * 8 + j;
    int src = (n * CC + ci) * 9 + pos;
    wq[idx]        = f2bf(w1[src]);
    wq[9216 + idx] = f2bf(w2[src]);
}

// Prepass: x fp32 NCHW -> bf16 NHWC (one pixel per thread; coalesced loads
// across threads, 64 B contiguous stores per thread).
__global__ __launch_bounds__(256)
void to_nhwc(const float* __restrict__ x, unsigned short* __restrict__ xbf) {
    int id = blockIdx.x * 256 + threadIdx.x;    // 0 .. B*H*W-1 (grid exact)
    int b  = id >> 16;
    int p  = id & 65535;
    const float* xp = x + (size_t)b * CC * HH * WW + p;
    U4 o[4];
    #pragma unroll
    for (int q = 0; q < 4; ++q) {
        float v0 = xp[(q * 8 + 0) * (HH * WW)];
        float v1 = xp[(q * 8 + 1) * (HH * WW)];
        float v2 = xp[(q * 8 + 2) * (HH * WW)];
        float v3 = xp[(q * 8 + 3) * (HH * WW)];
        float v4 = xp[(q * 8 + 4) * (HH * WW)];
        float v5 = xp[(q * 8 + 5) * (HH * WW)];
        float v6 = xp[(q * 8 + 6) * (HH * WW)];
        float v7 = xp[(q * 8 + 7) * (HH * WW)];
        o[q].lo.x = cvtpk(v0, v1); o[q].lo.y = cvtpk(v2, v3);
        o[q].hi.x = cvtpk(v4, v5); o[q].hi.y = cvtpk(v6, v7);
    }
    U4* dst = (U4*)(xbf + ((size_t)b * HH * WW + p) * CC);
    dst[0] = o[0]; dst[1] = o[1]; dst[2] = o[2]; dst[3] = o[3];
}

// Fully fused: conv1 (bias1*gate, relu) -> LDS ring -> conv2 (bias2*gate, relu) + resid.
// T14 async-stage (lean): 4x16B bf16 loads per pixel issued before conv1(i)'s MFMA body,
// ds_writes after B1. No conversion, 16-32 in-flight VGPRs.
__global__ __launch_bounds__(256, 2)
void conv_fused(const unsigned short* __restrict__ xbf,  // bf16 NHWC input
                const float* __restrict__ x,             // fp32 NCHW (residual)
                const unsigned short* __restrict__ wq,   // layer1 table; layer2 at +9216 ushorts
                const float* __restrict__ b1v,
                const float* __restrict__ b2v,
                const float* __restrict__ gate,
                float* __restrict__ out)
{
    __shared__ unsigned short xs[TH + 2][34][CIP];      // 10*34*36*2 = 24480 B
    __shared__ unsigned short hs[2][TH][34][CIP];       // 2*8*34*36*2 = 39168 B (cols 32,33 pad)
    __shared__ float gs[CC], bs1[CC], bs2[CC];

    const int t     = threadIdx.x;
    const int b     = blockIdx.z;
    const int x0    = blockIdx.x * TWV;
    const int ybase = blockIdx.y * (TH * NT);

    if (t < CC) {
        float gv = gate[b * CC + t];
        gs[t]  = gv > 0.f ? gv : 0.f;
        bs1[t] = b1v[t];
        bs2[t] = b2v[t];
    }

    const int lane = t & 63;
    const int wv   = t >> 6;       // wave 0..3
    const int col  = lane & 31;    // MFMA n (pixel/col) and A m (co) lane index
    const int half = lane >> 5;
    const int r0 = wv * 2, r1 = r0 + 1;

    // Both layers' weight fragments (L2-hot 36KB table).
    // NOTE: U4 = 8 ushorts, so layer-2 base is wq + 9216 (ushorts).
    bf16x8 wf1[18], wf2[18];
    const U4* wq1 = (const U4*)wq;
    const U4* wq2 = (const U4*)(wq + 9216);
    #pragma unroll
    for (int st = 0; st < 18; ++st) {
        wf1[st] = __builtin_bit_cast(bf16x8, wq1[(st * 2 + half) * 32 + col]);
        wf2[st] = __builtin_bit_cast(bf16x8, wq2[(st * 2 + half) * 32 + col]);
    }

    // Pixel-per-thread staging decomposition (340 = 10x34 pixels; 84 threads own 2).
    const int yA = t / 34,        xA = t - yA * 34;
    const int pB = 256 + t;
    const int yB = pB / 34,       xB = pB - yB * 34;
    const bool hasB = t < 84;
    const unsigned short* xbfb = xbf + (size_t)b * HH * WW * CC;

    // In-flight staging registers: 4 U4 per owned pixel (16/32 VGPR total).
    U4 sa0, sa1, sa2, sa3, sb0, sb1, sb2, sb3;

    // Issue bf16 NHWC loads for x rows [rowT, rowT+9] x cols [x0-2, x0+31].
    auto stage_load = [&](int rowT) {
        sa0.lo = {0u,0u}; sa0.hi = {0u,0u}; sa1 = sa0; sa2 = sa0; sa3 = sa0;
        sb0 = sa0; sb1 = sa0; sb2 = sa0; sb3 = sa0;
        const int gyA = rowT + yA, gxA = x0 - 2 + xA;
        if (gyA >= 0 && gyA < HH && gxA >= 0 && gxA < WW) {
            const U4* p = (const U4*)(xbfb + (size_t)(gyA * WW + gxA) * CC);
            sa0 = p[0]; sa1 = p[1]; sa2 = p[2]; sa3 = p[3];
        }
        const int gyB = rowT + yB, gxB = x0 - 2 + xB;
        if (hasB && gyB >= 0 && gyB < HH && gxB >= 0 && gxB < WW) {
            const U4* p = (const U4*)(xbfb + (size_t)(gyB * WW + gxB) * CC);
            sb0 = p[0]; sb1 = p[1]; sb2 = p[2]; sb3 = p[3];
        }
    };
    // Write the in-flight registers into xs (8-B aligned slots, no conversion).
    auto stage_write = [&]() {
        *(U2*)&xs[yA][xA][0]  = sa0.lo; *(U2*)&xs[yA][xA][4]  = sa0.hi;
        *(U2*)&xs[yA][xA][8]  = sa1.lo; *(U2*)&xs[yA][xA][12] = sa1.hi;
        *(U2*)&xs[yA][xA][16] = sa2.lo; *(U2*)&xs[yA][xA][20] = sa2.hi;
        *(U2*)&xs[yA][xA][24] = sa3.lo; *(U2*)&xs[yA][xA][28] = sa3.hi;
        if (hasB) {
            *(U2*)&xs[yB][xB][0]  = sb0.lo; *(U2*)&xs[yB][xB][4]  = sb0.hi;
            *(U2*)&xs[yB][xB][8]  = sb1.lo; *(U2*)&xs[yB][xB][12] = sb1.hi;
            *(U2*)&xs[yB][xB][16] = sb2.lo; *(U2*)&xs[yB][xB][20] = sb2.hi;
            *(U2*)&xs[yB][xB][24] = sb3.lo; *(U2*)&xs[yB][xB][28] = sb3.hi;
        }
    };

    // conv1 iteration i: rows gR = ybase-1+8i+r (r=0..7), cols gC = x0-1+c (c=0..31).
    // Output -> hs[i&1], zero-masked outside the image (conv2 SAME padding).
    auto conv1_iter = [&](int i) {
        f32x16 acc0 = {0,0,0,0,0,0,0,0,0,0,0,0,0,0,0,0};
        f32x16 acc1 = {0,0,0,0,0,0,0,0,0,0,0,0,0,0,0,0};
        const unsigned short* xsb0 = &xs[r0][col][half * 8];
        const unsigned short* xsb1 = &xs[r1][col][half * 8];
        #pragma unroll
        for (int st = 0; st < 18; ++st) {
            const int pos = st >> 1, s = st & 1;
            const int kh = pos / 3, kw = pos - kh * 3;
            const int off = (kh * 34 + kw) * CIP + s * 16;
            U4 xa, xv;
            xa.lo = *(const U2*)(xsb0 + off);
            xa.hi = *(const U2*)(xsb0 + off + 4);
            xv.lo = *(const U2*)(xsb1 + off);
            xv.hi = *(const U2*)(xsb1 + off + 4);
            acc0 = __builtin_amdgcn_mfma_f32_32x32x16_bf16(wf1[st], __builtin_bit_cast(bf16x8, xa), acc0, 0, 0, 0);
            acc1 = __builtin_amdgcn_mfma_f32_32x32x16_bf16(wf1[st], __builtin_bit_cast(bf16x8, xv), acc1, 0, 0, 0);
        }
        const int rowbase = ybase - 1 + 8 * i;
        const int gR0 = rowbase + r0, gR1 = rowbase + r1;
        const int gC  = x0 - 1 + col;
        const bool okC = (unsigned)gC < (unsigned)WW;
        const bool ok0 = okC && ((unsigned)gR0 < (unsigned)HH);
        const bool ok1 = okC && ((unsigned)gR1 < (unsigned)HH);
        unsigned short* h0 = &hs[i & 1][r0][col][0];
        unsigned short* h1 = &hs[i & 1][r1][col][0];
        #pragma unroll
        for (int g = 0; g < 4; ++g) {
            int c0 = 8 * g + 4 * half;    // regs 4g..4g+3 -> consecutive co
            float a0 = fmaxf((acc0[4 * g + 0] + bs1[c0 + 0]) * gs[c0 + 0], 0.f);
            float a1 = fmaxf((acc0[4 * g + 1] + bs1[c0 + 1]) * gs[c0 + 1], 0.f);
            float a2 = fmaxf((acc0[4 * g + 2] + bs1[c0 + 2]) * gs[c0 + 2], 0.f);
            float a3 = fmaxf((acc0[4 * g + 3] + bs1[c0 + 3]) * gs[c0 + 3], 0.f);
            if (!ok0) { a0 = 0.f; a1 = 0.f; a2 = 0.f; a3 = 0.f; }
            U2 w0; w0.x = cvtpk(a0, a1); w0.y = cvtpk(a2, a3);
            *(U2*)(h0 + c0) = w0;
            float d0 = fmaxf((acc1[4 * g + 0] + bs1[c0 + 0]) * gs[c0 + 0], 0.f);
            float d1 = fmaxf((acc1[4 * g + 1] + bs1[c0 + 1]) * gs[c0 + 1], 0.f);
            float d2 = fmaxf((acc1[4 * g + 2] + bs1[c0 + 2]) * gs[c0 + 2], 0.f);
            float d3 = fmaxf((acc1[4 * g + 3] + bs1[c0 + 3]) * gs[c0 + 3], 0.f);
            if (!ok1) { d0 = 0.f; d1 = 0.f; d2 = 0.f; d3 = 0.f; }
            U2 w1; w1.x = cvtpk(d0, d1); w1.y = cvtpk(d2, d3);
            *(U2*)(h1 + c0) = w1;
        }
    };

    // conv2 iteration j: output rows gO = ybase+8j+r, cols gX = x0+n (n<30 valid).
    // Input row gO-1+kh lives in hs bank (j+(q>>3))&1, slot q&7, q = r+kh.
    auto conv2_iter = [&](int j) {
        f32x16 acc0 = {0,0,0,0,0,0,0,0,0,0,0,0,0,0,0,0};
        f32x16 acc1 = {0,0,0,0,0,0,0,0,0,0,0,0,0,0,0,0};
        const unsigned short* hb0 = &hs[j & 1][0][0][0];
        const unsigned short* hb1 = &hs[(j + 1) & 1][0][0][0];
        if (wv < 3) {
            // q = r+kh <= 7: everything in bank j&1, constant offsets.
            const unsigned short* p0 = hb0 + (r0 * 34 + col) * CIP + half * 8;
            const unsigned short* p1 = hb0 + (r1 * 34 + col) * CIP + half * 8;
            #pragma unroll
            for (int st = 0; st < 18; ++st) {
                const int pos = st >> 1, s = st & 1;
                const int kh = pos / 3, kw = pos - kh * 3;
                const int off = (kh * 34 + kw) * CIP + s * 16;
                U4 xa, xv;
                xa.lo = *(const U2*)(p0 + off);
                xa.hi = *(const U2*)(p0 + off + 4);
                xv.lo = *(const U2*)(p1 + off);
                xv.hi = *(const U2*)(p1 + off + 4);
                acc0 = __builtin_amdgcn_mfma_f32_32x32x16_bf16(wf2[st], __builtin_bit_cast(bf16x8, xa), acc0, 0, 0, 0);
                acc1 = __builtin_amdgcn_mfma_f32_32x32x16_bf16(wf2[st], __builtin_bit_cast(bf16x8, xv), acc1, 0, 0, 0);
            }
        } else {
            // wv==3: r0=6, r1=7 -> q0 = 6+kh in {6,7,8}, q1 = 7+kh in {7,8,9}; bank split compile-time.
            const unsigned short* c0p = hb0 + col * CIP + half * 8;
            const unsigned short* c1p = hb1 + col * CIP + half * 8;
            #pragma unroll
            for (int st = 0; st < 18; ++st) {
                const int pos = st >> 1, s = st & 1;
                const int kh = pos / 3, kw = pos - kh * 3;
                const int q0 = 6 + kh, q1 = 7 + kh;
                const unsigned short* p0 = (q0 >= 8 ? c1p : c0p) + ((q0 & 7) * 34 + kw) * CIP + s * 16;
                const unsigned short* p1 = (q1 >= 8 ? c1p : c0p) + ((q1 & 7) * 34 + kw) * CIP + s * 16;
                U4 xa, xv;
                xa.lo = *(const U2*)(p0);
                xa.hi = *(const U2*)(p0 + 4);
                xv.lo = *(const U2*)(p1);
                xv.hi = *(const U2*)(p1 + 4);
                acc0 = __builtin_amdgcn_mfma_f32_32x32x16_bf16(wf2[st], __builtin_bit_cast(bf16x8, xa), acc0, 0, 0, 0);
                acc1 = __builtin_amdgcn_mfma_f32_32x32x16_bf16(wf2[st], __builtin_bit_cast(bf16x8, xv), acc1, 0, 0, 0);
            }
        }
        const int gO0 = ybase + 8 * j + r0;
        const int gO1 = gO0 + 1;
        const int gX  = x0 + col;
        const bool okN = (col < TWV) && (gX < WW);
        float* ob = out + (size_t)b * CC * HH * WW;
        const float* rb = x + (size_t)b * CC * HH * WW;
        if (okN) {
            #pragma unroll
            for (int reg = 0; reg < 16; ++reg) {
                int co = (reg & 3) + 8 * (reg >> 2) + 4 * half;
                int i0 = (co * HH + gO0) * WW + gX;
                int i1 = (co * HH + gO1) * WW + gX;
                float v0 = (acc0[reg] + bs2[co]) * gs[co];
                float v1 = (acc1[reg] + bs2[co]) * gs[co];
                ob[i0] = fmaxf(v0, 0.f) + rb[i0];
                ob[i1] = fmaxf(v1, 0.f) + rb[i1];
            }
        }
    };

    // ---- schedule: conv1 one iteration ahead of conv2; stage loads one ahead of writes ----
    stage_load(ybase - 2);
    stage_write();
    __syncthreads();                     // xs(0) ready (also fences gs/bs)
    stage_load(ybase - 2 + 8);           // loads for tile 1 fly under conv1(0)
    conv1_iter(0);
    #pragma unroll 1
    for (int i = 1; i <= NT; ++i) {
        __syncthreads();                 // B1: conv1(i-1) xs reads done; conv2(i-2) hs reads done
        stage_write();                   // xs <- tile i (loads long since returned)
        __syncthreads();                 // B2: xs(i) ready
        if (i < NT) stage_load(ybase - 2 + 8 * (i + 1));  // fly under conv1(i)+conv2(i-1)
        conv1_iter(i);                   // -> hs[i&1]
        __syncthreads();                 // B3: hs[i&1] visible
        conv2_iter(i - 1);               // reads hs[(i-1)&1] + hs[i&1] rows 0..1
    }
}

extern "C" void kernel_launch(void* const* d_in, const int* in_sizes, int n_in,
                              void* d_out, int out_size, void* d_ws, size_t ws_size,
                              hipStream_t stream) {
    const float* x  = (const float*)d_in[0];
    const float* gv = (const float*)d_in[1];
    const float* w1 = (const float*)d_in[2];
    const float* b1 = (const float*)d_in[3];
    const float* w2 = (const float*)d_in[4];
    const float* b2 = (const float*)d_in[5];
    float* out = (float*)d_out;

    unsigned short* xbf = (unsigned short*)d_ws;          // bf16 NHWC x: 64 MiB
    unsigned short* wq  = xbf + (size_t)BB * HH * WW * CC; // 2 x 9216 bf16 frag tables

    wprep<<<36, 256, 0, stream>>>(w1, w2, wq);
    to_nhwc<<<BB * HH * WW / 256, 256, 0, stream>>>(x, xbf);

    dim3 grid((WW + TWV - 1) / TWV, HH / (TH * NT), BB);  // (9, 8, 16) = 1152 blocks
    conv_fused<<<grid, 256, 0, stream>>>(xbf, x, wq, b1, b2, gv, out);
}